// Round 5
// baseline (1810.686 us; speedup 1.0000x reference)
//
#include <hip/hip_runtime.h>
#include <hip/hip_bf16.h>
#include <math.h>

typedef __hip_bfloat16 bf16;
typedef __attribute__((ext_vector_type(8))) short bf16x8;
typedef __attribute__((ext_vector_type(4))) float f32x4;

#define B_ 4
#define S_ 2048
#define H_ 768
#define NH_ 12
#define HD_ 64
#define E_ 8
#define F_ 3072
#define T_ 8192     // B_*S_

__device__ __forceinline__ unsigned f2bf(float x){   // RNE f32->bf16 bits
  unsigned u = __float_as_uint(x);
  return (u + 0x7FFFu + ((u >> 16) & 1u)) >> 16;
}

__device__ __forceinline__ float4 ldA4(const float* p){ return *reinterpret_cast<const float4*>(p); }

__device__ __forceinline__ float block_sum256(float v, float* red){
  int tid = threadIdx.x;
  red[tid] = v; __syncthreads();
  #pragma unroll
  for (int s = 128; s > 0; s >>= 1){
    if (tid < s) red[tid] += red[tid + s];
    __syncthreads();
  }
  float r = red[0];
  __syncthreads();
  return r;
}

// ---------------- f32 VALU GEMM, 128x128 tile, 8x8 register tile: C = A * B ----------------
// Bit-identical accumulation order to the round-1 gemm_k (BK=16, kk ascending).
// Fixes vs round 4: (1) staggered Bs columns (4-way -> 2-way bank conflicts on read),
// (2) single-barrier double-buffered LDS with register prefetch (hides HBM latency),
// (3) bijective XCD swizzle (A-panel L2 locality). All perf-only, arithmetic unchanged.
__global__ __launch_bounds__(256) void gemm_f32_k(const float* __restrict__ A, const float* __restrict__ Bw,
                                                  float* __restrict__ C, int N, int K)
{
  __shared__ float As[2][16][132];   // [buf][k][m]
  __shared__ float Bs[2][16][140];   // [buf][k][staggered n]
  const int tid = threadIdx.x;
  const int gx = gridDim.x;
  const int nwg = gx * gridDim.y;          // both call sites: nwg % 8 == 0
  const int bid = blockIdx.y * gx + blockIdx.x;
  const int cpx = nwg >> 3;
  const int swz = (bid & 7) * cpx + (bid >> 3);
  const int m0 = (swz / gx) * 128, n0 = (swz % gx) * 128;

  const int tm = tid >> 4, tn = tid & 15;
  const int am = tid >> 1, akq = (tid & 1) * 8;   // A staging: row am, k-octet akq
  const int bk = tid >> 4, bo = tid & 15;         // B staging: k-row bk, col-octet bo
  const int bg = bo * 8 + ((bo >> 2) << 2);       // staggered LDS col offset (write)
  const int tg = tn * 8 + ((tn >> 2) << 2);       // staggered LDS col offset (read)
  float acc[8][8] = {};

  const float* Aptr = A + (size_t)(m0 + am) * K + akq;
  const float* Bptr = Bw + (size_t)bk * N + n0 + bo * 8;

  // prologue: load tile 0 and stage into buf 0
  float4 a0 = ldA4(Aptr);
  float4 a1 = ldA4(Aptr + 4);
  float4 b0 = ldA4(Bptr);
  float4 b1 = ldA4(Bptr + 4);
  As[0][akq+0][am]=a0.x; As[0][akq+1][am]=a0.y; As[0][akq+2][am]=a0.z; As[0][akq+3][am]=a0.w;
  As[0][akq+4][am]=a1.x; As[0][akq+5][am]=a1.y; As[0][akq+6][am]=a1.z; As[0][akq+7][am]=a1.w;
  *reinterpret_cast<float4*>(&Bs[0][bk][bg])   = b0;
  *reinterpret_cast<float4*>(&Bs[0][bk][bg+4]) = b1;

  int buf = 0;
  for (int k0 = 16; k0 <= K; k0 += 16){
    const bool more = (k0 < K);
    __syncthreads();                       // staged writes of cur visible; other buf free
    if (more){                             // prefetch next tile into registers
      a0 = ldA4(Aptr + k0);
      a1 = ldA4(Aptr + k0 + 4);
      b0 = ldA4(Bptr + (size_t)k0 * N);
      b1 = ldA4(Bptr + (size_t)k0 * N + 4);
    }
    #pragma unroll
    for (int kk = 0; kk < 16; ++kk){
      float4 av0 = *reinterpret_cast<const float4*>(&As[buf][kk][tm*8]);
      float4 av1 = *reinterpret_cast<const float4*>(&As[buf][kk][tm*8 + 4]);
      float4 bv0 = *reinterpret_cast<const float4*>(&Bs[buf][kk][tg]);
      float4 bv1 = *reinterpret_cast<const float4*>(&Bs[buf][kk][tg + 4]);
      float a[8] = {av0.x,av0.y,av0.z,av0.w,av1.x,av1.y,av1.z,av1.w};
      float b[8] = {bv0.x,bv0.y,bv0.z,bv0.w,bv1.x,bv1.y,bv1.z,bv1.w};
      #pragma unroll
      for (int i = 0; i < 8; ++i)
        #pragma unroll
        for (int j = 0; j < 8; ++j)
          acc[i][j] += a[i]*b[j];
    }
    if (!more) break;
    const int ob = buf ^ 1;                // stage next tile into other buf (no barrier needed:
    As[ob][akq+0][am]=a0.x; As[ob][akq+1][am]=a0.y; As[ob][akq+2][am]=a0.z; As[ob][akq+3][am]=a0.w;
    As[ob][akq+4][am]=a1.x; As[ob][akq+5][am]=a1.y; As[ob][akq+6][am]=a1.z; As[ob][akq+7][am]=a1.w;
    *reinterpret_cast<float4*>(&Bs[ob][bk][bg])   = b0;   // readers of ob finished before the
    *reinterpret_cast<float4*>(&Bs[ob][bk][bg+4]) = b1;   // barrier at the top of this iter)
    buf = ob;
  }
  #pragma unroll
  for (int i = 0; i < 8; ++i){
    int row = m0 + tm*8 + i;
    float* dst = &C[(size_t)row * N + n0 + tn*8];
    *reinterpret_cast<float4*>(dst)     = make_float4(acc[i][0], acc[i][1], acc[i][2], acc[i][3]);
    *reinterpret_cast<float4*>(dst + 4) = make_float4(acc[i][4], acc[i][5], acc[i][6], acc[i][7]);
  }
}

// ---------------- RoPE in-place on q,k inside qkv buffer ----------------
__global__ __launch_bounds__(256) void rope_k(float* __restrict__ qkv)
{
  int idx = blockIdx.x * 256 + threadIdx.x;
  int j  = idx & 31;
  int hh = (idx >> 5) % NH_;
  int t  = idx / (32 * NH_);
  int s  = t & (S_ - 1);
  double invf = pow(10000.0, -(double)j / 32.0);
  float ph = (float)((double)s * invf);
  float sn, cs;
  sincosf(ph, &sn, &cs);
  float* base = qkv + (size_t)t * 2304 + hh * 192;
  float q0 = base[j],    q1 = base[32+j];
  base[j]    = q0*cs - q1*sn;
  base[32+j] = q1*cs + q0*sn;
  float k0 = base[64+j], k1 = base[96+j];
  base[64+j] = k0*cs - k1*sn;
  base[96+j] = k1*cs + k0*sn;
}

// ---------------- MFMA flash attention (bf16 inputs, f32 accum) ----------------
// One block = (b, h, 64 q rows); 4 waves, each owns 16 q rows. KV tile = 64.
// LDS tiles are [row][72] shorts with col ^= ((row&12)<<1) XOR swizzle:
//   keeps every staged write and every b128 fragment read at <=2-way bank aliasing.
__global__ __launch_bounds__(256) void attn_mfma_k(const float* __restrict__ qkv,
                                                   const int* __restrict__ amask,
                                                   float* __restrict__ ctx)
{
  __shared__ __align__(16) short Kl[64*72];   // K tile bf16  [kv][d]
  __shared__ __align__(16) short Vt[64*72];   // V^T tile bf16 [d][kv]
  __shared__ __align__(16) short Pl[64*72];   // P tile bf16  [q][kv] (per-wave 16-row slices)
  const int tid = threadIdx.x;
  const int qt = blockIdx.x & 31;
  const int hh = (blockIdx.x >> 5) % NH_;
  const int b  = blockIdx.x / (32 * NH_);
  const size_t tb = (size_t)b * S_;
  const int q0 = qt * 64;
  const int lane = tid & 63, w = tid >> 6;
  const int quad = lane >> 4, l15 = lane & 15;
  const int swl = (l15 & 12) << 1;            // read-side swizzle key (row&12)<<1 with row=...+l15

  // Q fragments in registers: A-frag row = w*16 + l15, k = quad*8 + ks*32 + j. Pre-scaled by 1/8.
  bf16x8 qf[2];
  {
    const float* qrow = qkv + (tb + q0 + w*16 + l15) * 2304 + hh*192;
    #pragma unroll
    for (int ks = 0; ks < 2; ++ks){
      float4 f0 = ldA4(qrow + ks*32 + quad*8);
      float4 f1 = ldA4(qrow + ks*32 + quad*8 + 4);
      union { bf16x8 v; unsigned u[4]; } u;
      u.u[0] = f2bf(f0.x*0.125f) | (f2bf(f0.y*0.125f) << 16);
      u.u[1] = f2bf(f0.z*0.125f) | (f2bf(f0.w*0.125f) << 16);
      u.u[2] = f2bf(f1.x*0.125f) | (f2bf(f1.y*0.125f) << 16);
      u.u[3] = f2bf(f1.z*0.125f) | (f2bf(f1.w*0.125f) << 16);
      qf[ks] = u.v;
    }
  }

  f32x4 O[4];                                  // O[nd][r]: row = w*16+quad*4+r, d = nd*16+l15
  #pragma unroll
  for (int i = 0; i < 4; ++i) O[i] = (f32x4){0.f,0.f,0.f,0.f};
  float m_i[4] = {-3.0e38f,-3.0e38f,-3.0e38f,-3.0e38f};
  float l_i[4] = {0.f,0.f,0.f,0.f};

  for (int c = 0; c < 32; ++c){
    __syncthreads();   // all waves done reading Kl/Vt of previous tile
    // ---- stage K [kv][d] and V^T [d][kv] (f32 -> bf16), 512 slots of (2 kv-rows x 4 d) ----
    #pragma unroll
    for (int i = 0; i < 2; ++i){
      int idx = i*256 + tid;
      int rp = idx >> 4;                 // kv row-pair 0..31
      int c4 = (idx & 15) * 4;           // d group
      int r = rp * 2;
      const float* src = &qkv[(tb + c*64 + r) * 2304 + hh*192 + 64 + c4];
      float4 k0 = ldA4(src);
      float4 v0 = ldA4(src + 64);
      float4 k1 = ldA4(src + 2304);
      float4 v1 = ldA4(src + 2304 + 64);
      uint2 kw0, kw1;
      kw0.x = f2bf(k0.x) | (f2bf(k0.y) << 16); kw0.y = f2bf(k0.z) | (f2bf(k0.w) << 16);
      kw1.x = f2bf(k1.x) | (f2bf(k1.y) << 16); kw1.y = f2bf(k1.z) | (f2bf(k1.w) << 16);
      *reinterpret_cast<uint2*>(&Kl[ r   *72 + (c4 ^ (( r    & 12) << 1))]) = kw0;
      *reinterpret_cast<uint2*>(&Kl[(r+1)*72 + (c4 ^ (((r+1) & 12) << 1))]) = kw1;
      float vv0[4] = {v0.x,v0.y,v0.z,v0.w};
      float vv1[4] = {v1.x,v1.y,v1.z,v1.w};
      #pragma unroll
      for (int dd = 0; dd < 4; ++dd){
        int d = c4 + dd;
        unsigned pw = f2bf(vv0[dd]) | (f2bf(vv1[dd]) << 16);   // pack kv pair (r, r+1)
        *reinterpret_cast<unsigned*>(&Vt[d*72 + (r ^ ((d & 12) << 1))]) = pw;
      }
    }
    __syncthreads();

    // ---- S = Q K^T (per wave: 16 q rows x 64 kv cols) ----
    f32x4 sacc[4];
    #pragma unroll
    for (int ni = 0; ni < 4; ++ni) sacc[ni] = (f32x4){0.f,0.f,0.f,0.f};
    #pragma unroll
    for (int ks = 0; ks < 2; ++ks){
      #pragma unroll
      for (int ni = 0; ni < 4; ++ni){
        bf16x8 kf = *reinterpret_cast<const bf16x8*>(
            &Kl[(ni*16 + l15)*72 + ((quad*8 + ks*32) ^ swl)]);
        sacc[ni] = __builtin_amdgcn_mfma_f32_16x16x32_bf16(qf[ks], kf, sacc[ni], 0, 0, 0);
      }
    }

    // ---- mask + online softmax (rows = quad*4+r, cols = ni*16+l15) ----
    #pragma unroll
    for (int ni = 0; ni < 4; ++ni){
      int mv = amask[b*S_ + c*64 + ni*16 + l15];
      if (mv == 0){
        sacc[ni][0] = -3.0e38f; sacc[ni][1] = -3.0e38f;
        sacc[ni][2] = -3.0e38f; sacc[ni][3] = -3.0e38f;
      }
    }
    float p[4][4];
    #pragma unroll
    for (int r = 0; r < 4; ++r){
      float v = fmaxf(fmaxf(sacc[0][r], sacc[1][r]), fmaxf(sacc[2][r], sacc[3][r]));
      #pragma unroll
      for (int o = 8; o > 0; o >>= 1) v = fmaxf(v, __shfl_xor(v, o, 64));
      float mn = fmaxf(m_i[r], v);
      float al = __expf(m_i[r] - mn);
      m_i[r] = mn;
      float ts = 0.f;
      #pragma unroll
      for (int ni = 0; ni < 4; ++ni){
        float e = __expf(sacc[ni][r] - mn);
        p[ni][r] = e; ts += e;
      }
      #pragma unroll
      for (int o = 8; o > 0; o >>= 1) ts += __shfl_xor(ts, o, 64);
      l_i[r] = l_i[r]*al + ts;
      #pragma unroll
      for (int nd = 0; nd < 4; ++nd) O[nd][r] *= al;
    }

    // ---- P C-layout -> LDS (bf16) -> A-layout fragments (per-wave rows, no barrier) ----
    #pragma unroll
    for (int ni = 0; ni < 4; ++ni){
      int colp = (ni*16 + l15) ^ (quad << 3);   // ((q&12)<<1) == quad<<3 for rows quad*4+r
      #pragma unroll
      for (int r = 0; r < 4; ++r)
        Pl[(w*16 + quad*4 + r)*72 + colp] = (short)f2bf(p[ni][r]);
    }
    bf16x8 pa[2];
    #pragma unroll
    for (int ks = 0; ks < 2; ++ks)
      pa[ks] = *reinterpret_cast<const bf16x8*>(
          &Pl[(w*16 + l15)*72 + ((quad*8 + ks*32) ^ swl)]);

    // ---- O += P V ----
    #pragma unroll
    for (int ks = 0; ks < 2; ++ks){
      #pragma unroll
      for (int nd = 0; nd < 4; ++nd){
        bf16x8 vf = *reinterpret_cast<const bf16x8*>(
            &Vt[(nd*16 + l15)*72 + ((quad*8 + ks*32) ^ swl)]);
        O[nd] = __builtin_amdgcn_mfma_f32_16x16x32_bf16(pa[ks], vf, O[nd], 0, 0, 0);
      }
    }
  }

  // ---- epilogue: O / l ----
  #pragma unroll
  for (int r = 0; r < 4; ++r){
    float inv = 1.f / l_i[r];
    int row = q0 + w*16 + quad*4 + r;
    float* dst = &ctx[(tb + row)*H_ + hh*HD_ + l15];
    #pragma unroll
    for (int nd = 0; nd < 4; ++nd)
      dst[nd*16] = O[nd][r] * inv;
  }
}

// ---------------- norm1: x1 = rmsnorm(x + attn_out) * w ----------------
__global__ __launch_bounds__(256) void norm1_k(const float* __restrict__ x, const float* __restrict__ ao,
                                               const float* __restrict__ w, float* __restrict__ x1)
{
  __shared__ float red[256];
  const int t = blockIdx.x, tid = threadIdx.x;
  float y[3]; float ss = 0.f;
  #pragma unroll
  for (int k = 0; k < 3; ++k){
    int i = tid + k*256;
    y[k] = x[(size_t)t*H_ + i] + ao[(size_t)t*H_ + i];
    ss += y[k]*y[k];
  }
  float tot = block_sum256(ss, red);
  float r = rsqrtf(tot / 768.f + 1.1920928955078125e-07f);
  #pragma unroll
  for (int k = 0; k < 3; ++k){
    int i = tid + k*256;
    x1[(size_t)t*H_ + i] = y[k] * r * w[i];
  }
}

// ---------------- router: logits, softmax, top-2, stats ----------------
__global__ __launch_bounds__(256) void router_k(const float* __restrict__ x1, const float* __restrict__ gw,
                                                float* __restrict__ rw, int* __restrict__ sel,
                                                float* __restrict__ Psum, int* __restrict__ cnt)
{
  __shared__ float lg[8];
  __shared__ float pr[8];
  const int t = blockIdx.x, tid = threadIdx.x;
  const int e = tid >> 5, l = tid & 31;
  const float* xr = x1 + (size_t)t * H_;
  float p = 0.f;
  for (int k = l; k < H_; k += 32) p += xr[k] * gw[k*E_ + e];
  #pragma unroll
  for (int o = 16; o > 0; o >>= 1) p += __shfl_xor(p, o, 32);
  if (l == 0) lg[e] = p;
  __syncthreads();
  if (tid == 0){
    float m = lg[0];
    #pragma unroll
    for (int i = 1; i < 8; ++i) m = fmaxf(m, lg[i]);
    float pv[8]; float s = 0.f;
    #pragma unroll
    for (int i = 0; i < 8; ++i){ pv[i] = expf(lg[i] - m); s += pv[i]; }
    float invs = 1.f / s;
    #pragma unroll
    for (int i = 0; i < 8; ++i){ pv[i] *= invs; pr[i] = pv[i]; }
    int i0 = 0;
    for (int i = 1; i < 8; ++i) if (pv[i] > pv[i0]) i0 = i;
    int i1 = -1;
    for (int i = 0; i < 8; ++i){ if (i == i0) continue; if (i1 < 0 || pv[i] > pv[i1]) i1 = i; }
    float w0 = pv[i0], w1 = pv[i1], si = 1.f / (w0 + w1);
    rw[2*t] = w0*si; rw[2*t+1] = w1*si;
    sel[2*t] = i0;   sel[2*t+1] = i1;
    atomicAdd(&cnt[i0], 1); atomicAdd(&cnt[i1], 1);
  }
  __syncthreads();
  if (tid < 8) atomicAdd(&Psum[tid], pr[tid]);
}

// ---------------- offsets + aux loss ----------------
__global__ void offs_aux_k(const float* __restrict__ Psum, const int* __restrict__ cnt,
                           int* __restrict__ offs, float* __restrict__ aux_out)
{
  __shared__ float red[8];
  const int tid = threadIdx.x;
  if (tid == 0){
    int o = 0;
    for (int e = 0; e < 8; ++e){ offs[e] = o; o += cnt[e]; }
  }
  if (tid < 8) red[tid] = ((float)cnt[tid] / 8192.f) * (Psum[tid] / 8192.f);
  __syncthreads();
  if (tid == 0){
    float s = 0.f;
    for (int e = 0; e < 8; ++e) s += red[e];
    *aux_out = 8.f * s;
  }
}

// ---------------- scatter tokens into per-expert segments (+ per-assignment weight) ----------------
__global__ __launch_bounds__(256) void scatter_k(const int* __restrict__ sel, const int* __restrict__ offs,
                                                 const float* __restrict__ rw,
                                                 int* __restrict__ cur, int* __restrict__ toka,
                                                 float* __restrict__ wgt)
{
  int t = blockIdx.x*256 + threadIdx.x;
  if (t >= T_) return;
  #pragma unroll
  for (int j = 0; j < 2; ++j){
    int e = sel[2*t + j];
    int pos = atomicAdd(&cur[e], 1);
    int a = offs[e] + pos;
    toka[a] = t;
    wgt[a] = rw[2*t + j];
  }
}

// ---------------- tiled transpose + f32->bf16 convert: dst[C][R] = src[R][C] ----------------
__global__ __launch_bounds__(256) void transpose_conv_k(const float* __restrict__ src,
                                                        unsigned short* __restrict__ dst,
                                                        int R, int C)
{
  __shared__ float T[32][33];
  const float* s = src + (size_t)blockIdx.z * R * C;
  unsigned short* d = dst + (size_t)blockIdx.z * R * C;
  int r0 = blockIdx.y*32, c0 = blockIdx.x*32;
  int t = threadIdx.x;
  int r = t >> 3, c4 = (t & 7) * 4;
  float4 v = ldA4(&s[(size_t)(r0+r)*C + c0 + c4]);
  T[r][c4+0]=v.x; T[r][c4+1]=v.y; T[r][c4+2]=v.z; T[r][c4+3]=v.w;
  __syncthreads();
  int c = t >> 3, r4 = (t & 7) * 4;
  ushort4 o;
  o.x = (unsigned short)f2bf(T[r4+0][c]);
  o.y = (unsigned short)f2bf(T[r4+1][c]);
  o.z = (unsigned short)f2bf(T[r4+2][c]);
  o.w = (unsigned short)f2bf(T[r4+3][c]);
  *reinterpret_cast<ushort4*>(&d[(size_t)(c0+c)*R + r0 + r4]) = o;
}

// ---------------- MoE GEMM1 (MFMA bf16): hmid = gelu(x1[toka] @ w1T^T) ----------------
// 128x128 tile, BK=64, 4 waves; A staged f32->bf16 on the fly; B pre-transposed [F][H] bf16.
__global__ __launch_bounds__(256) void moe1_mfma_k(const float* __restrict__ X,
                                                   const unsigned short* __restrict__ Bt,
                                                   const int* __restrict__ offs,
                                                   const int* __restrict__ cnts,
                                                   const int* __restrict__ toka,
                                                   unsigned short* __restrict__ hmid)
{
  const int e = blockIdx.z;
  const int n_e = cnts[e];
  const int mt = blockIdx.y * 128;
  if (mt >= n_e) return;
  const int base = offs[e];
  const unsigned short* Bw = Bt + (size_t)e * (H_*F_);
  __shared__ __align__(16) short Al[8*129*8];
  __shared__ __align__(16) short Bl[8*129*8];
  const int tid = threadIdx.x;
  const int n0 = blockIdx.x * 128;
  int tokm[4];
  #pragma unroll
  for (int i = 0; i < 4; ++i){
    int m = (tid + i*256) >> 3;
    tokm[i] = toka[base + min(mt + m, n_e - 1)];
  }
  const int lane = tid & 63, w = tid >> 6;
  const int wr = w >> 1, wc = w & 1;
  const int quad = lane >> 4, l15 = lane & 15;
  f32x4 acc[4][4];
  #pragma unroll
  for (int a = 0; a < 4; ++a)
    #pragma unroll
    for (int b = 0; b < 4; ++b) acc[a][b] = (f32x4){0.f,0.f,0.f,0.f};

  for (int k0 = 0; k0 < H_; k0 += 64){
    __syncthreads();
    #pragma unroll
    for (int i = 0; i < 4; ++i){
      int c = tid + i*256;
      int m = c >> 3, kc = c & 7;
      const float* src = X + (size_t)tokm[i]*H_ + k0 + kc*8;
      float4 f0 = ldA4(src);
      float4 f1 = ldA4(src + 4);
      int4 pk;
      pk.x = (int)(f2bf(f0.x) | (f2bf(f0.y) << 16));
      pk.y = (int)(f2bf(f0.z) | (f2bf(f0.w) << 16));
      pk.z = (int)(f2bf(f1.x) | (f2bf(f1.y) << 16));
      pk.w = (int)(f2bf(f1.z) | (f2bf(f1.w) << 16));
      *reinterpret_cast<int4*>(&Al[(kc*129 + m)*8]) = pk;
      *reinterpret_cast<int4*>(&Bl[(kc*129 + m)*8]) =
        *reinterpret_cast<const int4*>(&Bw[(size_t)(n0 + m)*H_ + k0 + kc*8]);
    }
    __syncthreads();
    #pragma unroll
    for (int ks = 0; ks < 2; ++ks){
      bf16x8 af[4], bfr[4];
      #pragma unroll
      for (int mi = 0; mi < 4; ++mi)
        af[mi] = *reinterpret_cast<const bf16x8*>(&Al[((ks*4+quad)*129 + wr*64 + mi*16 + l15)*8]);
      #pragma unroll
      for (int ni = 0; ni < 4; ++ni)
        bfr[ni] = *reinterpret_cast<const bf16x8*>(&Bl[((ks*4+quad)*129 + wc*64 + ni*16 + l15)*8]);
      #pragma unroll
      for (int mi = 0; mi < 4; ++mi)
        #pragma unroll
        for (int ni = 0; ni < 4; ++ni)
          acc[mi][ni] = __builtin_amdgcn_mfma_f32_16x16x32_bf16(af[mi], bfr[ni], acc[mi][ni], 0, 0, 0);
    }
  }
  #pragma unroll
  for (int mi = 0; mi < 4; ++mi)
    #pragma unroll
    for (int r = 0; r < 4; ++r){
      int row = mt + wr*64 + mi*16 + quad*4 + r;
      if (row < n_e){
        unsigned short* dst = hmid + (size_t)(base + row)*F_ + n0 + wc*64 + l15;
        #pragma unroll
        for (int ni = 0; ni < 4; ++ni){
          float h = acc[mi][ni][r];
          float g = 0.5f * h * (1.f + erff(h * 0.70710678118654752f));
          dst[ni*16] = (unsigned short)f2bf(g);
        }
      }
    }
}

// ---------------- MoE GEMM2 (MFMA bf16): x1 += wgt * (hmid @ w2T^T) ----------------
__global__ __launch_bounds__(256) void moe2_mfma_k(const unsigned short* __restrict__ Hm,
                                                   const unsigned short* __restrict__ Bt,
                                                   const int* __restrict__ offs,
                                                   const int* __restrict__ cnts,
                                                   const int* __restrict__ toka,
                                                   const float* __restrict__ wgt,
                                                   float* __restrict__ x1acc)
{
  const int e = blockIdx.z;
  const int n_e = cnts[e];
  const int mt = blockIdx.y * 128;
  if (mt >= n_e) return;
  const int base = offs[e];
  const unsigned short* Bw = Bt + (size_t)e * (H_*F_);
  __shared__ __align__(16) short Al[8*129*8];
  __shared__ __align__(16) short Bl[8*129*8];
  const int tid = threadIdx.x;
  const int n0 = blockIdx.x * 128;
  const int lane = tid & 63, w = tid >> 6;
  const int wr = w >> 1, wc = w & 1;
  const int quad = lane >> 4, l15 = lane & 15;
  f32x4 acc[4][4];
  #pragma unroll
  for (int a = 0; a < 4; ++a)
    #pragma unroll
    for (int b = 0; b < 4; ++b) acc[a][b] = (f32x4){0.f,0.f,0.f,0.f};

  for (int k0 = 0; k0 < F_; k0 += 64){
    __syncthreads();
    #pragma unroll
    for (int i = 0; i < 4; ++i){
      int c = tid + i*256;
      int m = c >> 3, kc = c & 7;
      int hrow = base + min(mt + m, n_e - 1);
      *reinterpret_cast<int4*>(&Al[(kc*129 + m)*8]) =
        *reinterpret_cast<const int4*>(&Hm[(size_t)hrow*F_ + k0 + kc*8]);
      *reinterpret_cast<int4*>(&Bl[(kc*129 + m)*8]) =
        *reinterpret_cast<const int4*>(&Bw[(size_t)(n0 + m)*F_ + k0 + kc*8]);
    }
    __syncthreads();
    #pragma unroll
    for (int ks = 0; ks < 2; ++ks){
      bf16x8 af[4], bfr[4];
      #pragma unroll
      for (int mi = 0; mi < 4; ++mi)
        af[mi] = *reinterpret_cast<const bf16x8*>(&Al[((ks*4+quad)*129 + wr*64 + mi*16 + l15)*8]);
      #pragma unroll
      for (int ni = 0; ni < 4; ++ni)
        bfr[ni] = *reinterpret_cast<const bf16x8*>(&Bl[((ks*4+quad)*129 + wc*64 + ni*16 + l15)*8]);
      #pragma unroll
      for (int mi = 0; mi < 4; ++mi)
        #pragma unroll
        for (int ni = 0; ni < 4; ++ni)
          acc[mi][ni] = __builtin_amdgcn_mfma_f32_16x16x32_bf16(af[mi], bfr[ni], acc[mi][ni], 0, 0, 0);
    }
  }
  #pragma unroll
  for (int mi = 0; mi < 4; ++mi)
    #pragma unroll
    for (int r = 0; r < 4; ++r){
      int row = mt + wr*64 + mi*16 + quad*4 + r;
      if (row < n_e){
        int tok = toka[base + row];
        float wg = wgt[base + row];
        float* dst = x1acc + (size_t)tok*H_ + n0 + wc*64 + l15;
        #pragma unroll
        for (int ni = 0; ni < 4; ++ni)
          atomicAdd(&dst[ni*16], acc[mi][ni][r] * wg);
      }
    }
}

// ---------------- norm2: out = rmsnorm(x1_accumulated) * w ----------------
__global__ __launch_bounds__(256) void norm2_k(const float* __restrict__ x1acc,
                                               const float* __restrict__ w, float* __restrict__ out)
{
  __shared__ float red[256];
  const int t = blockIdx.x, tid = threadIdx.x;
  const float* xr = x1acc + (size_t)t * H_;
  float y[3]; float ss = 0.f;
  #pragma unroll
  for (int k = 0; k < 3; ++k){
    int i = tid + k*256;
    y[k] = xr[i];
    ss += y[k]*y[k];
  }
  float tot = block_sum256(ss, red);
  float r = rsqrtf(tot / 768.f + 1.1920928955078125e-07f);
  #pragma unroll
  for (int k = 0; k < 3; ++k){
    int i = tid + k*256;
    out[(size_t)t*H_ + i] = y[k] * r * w[i];
  }
}

extern "C" void kernel_launch(void* const* d_in, const int* in_sizes, int n_in,
                              void* d_out, int out_size, void* d_ws, size_t ws_size,
                              hipStream_t stream)
{
  const float* x      = (const float*)d_in[0];
  const int*   amask  = (const int*)  d_in[1];
  const float* qkv_w  = (const float*)d_in[2];
  const float* out_w  = (const float*)d_in[3];
  const float* gate_w = (const float*)d_in[4];
  const float* w1     = (const float*)d_in[5];
  const float* w2     = (const float*)d_in[6];
  const float* n1w    = (const float*)d_in[7];
  const float* n2w    = (const float*)d_in[8];

  char* ws = (char*)d_ws;
  // workspace layout (bytes), liveness-overlapped; total ~163.8 MB:
  //   [0, 75497472)            qkv f32 (P1-P3) -> attn f32 [0,25165824) (P4-P5) -> hmid bf16 [0,100663296) (P7-P8)
  //   [75497472, 100663296)    ctx f32 (P3-P4) -> hmid tail
  //   [100663296, 125829120)   x1 f32 (norm1 -> router/moe1; moe2 atomically accumulates; norm2 reads)
  //   [125829120, 163577856)   w1T bf16 (conv -> moe1), then w2T bf16 (conv -> moe2)
  //   [163577856, ...)         rw / sel / toka / wgt / stats
  float* qkv  = (float*)(ws);
  float* ctx  = (float*)(ws + 75497472);
  float* attn = (float*)(ws);
  float* x1   = (float*)(ws + 100663296);
  unsigned short* hmid = (unsigned short*)(ws);
  unsigned short* w1T  = (unsigned short*)(ws + 125829120);
  unsigned short* w2T  = (unsigned short*)(ws + 125829120);
  float* rw   = (float*)(ws + 163577856);
  int*   sel  = (int*)  (ws + 163643392);
  int*   toka = (int*)  (ws + 163708928);
  float* wgt  = (float*)(ws + 163774464);
  float* Psum = (float*)(ws + 163840000);
  int*   cnt  = (int*)  (ws + 163840032);
  int*   cur  = (int*)  (ws + 163840064);
  int*   offs = (int*)  (ws + 163840096);

  float* out_x2  = (float*)d_out;
  float* out_aux = out_x2 + 6291456;

  hipMemsetAsync(ws + 163840000, 0, 128, stream);  // Psum, cnt, cur, offs

  gemm_f32_k<<<dim3(18, 64), 256, 0, stream>>>(x, qkv_w, qkv, 2304, H_);
  rope_k<<<12288, 256, 0, stream>>>(qkv);
  attn_mfma_k<<<1536, 256, 0, stream>>>(qkv, amask, ctx);
  gemm_f32_k<<<dim3(6, 64), 256, 0, stream>>>(ctx, out_w, attn, H_, H_);
  norm1_k<<<T_, 256, 0, stream>>>(x, attn, n1w, x1);
  router_k<<<T_, 256, 0, stream>>>(x1, gate_w, rw, sel, Psum, cnt);
  offs_aux_k<<<1, 64, 0, stream>>>(Psum, cnt, offs, out_aux);
  scatter_k<<<32, 256, 0, stream>>>(sel, offs, rw, cur, toka, wgt);
  transpose_conv_k<<<dim3(96, 24, 8), 256, 0, stream>>>(w1, w1T, H_, F_);   // w1T[e][F][H]
  moe1_mfma_k<<<dim3(24, 64, 8), 256, 0, stream>>>(x1, w1T, offs, cnt, toka, hmid);
  transpose_conv_k<<<dim3(24, 96, 8), 256, 0, stream>>>(w2, w2T, F_, H_);   // w2T[e][H][F]
  moe2_mfma_k<<<dim3(6, 64, 8), 256, 0, stream>>>(hmid, w2T, offs, cnt, toka, wgt, x1);
  norm2_k<<<T_, 256, 0, stream>>>(x1, n2w, out_x2);
}

// Round 6
// 1702.039 us; speedup vs baseline: 1.0638x; 1.0638x over previous
//
#include <hip/hip_runtime.h>
#include <hip/hip_bf16.h>
#include <math.h>

typedef __hip_bfloat16 bf16;
typedef __attribute__((ext_vector_type(8))) short bf16x8;
typedef __attribute__((ext_vector_type(4))) float f32x4;

#define B_ 4
#define S_ 2048
#define H_ 768
#define NH_ 12
#define HD_ 64
#define E_ 8
#define F_ 3072
#define T_ 8192     // B_*S_

__device__ __forceinline__ unsigned f2bf(float x){   // RNE f32->bf16 bits
  unsigned u = __float_as_uint(x);
  return (u + 0x7FFFu + ((u >> 16) & 1u)) >> 16;
}

__device__ __forceinline__ float4 ldA4(const float* p){ return *reinterpret_cast<const float4*>(p); }

__device__ __forceinline__ float block_sum256(float v, float* red){
  int tid = threadIdx.x;
  red[tid] = v; __syncthreads();
  #pragma unroll
  for (int s = 128; s > 0; s >>= 1){
    if (tid < s) red[tid] += red[tid + s];
    __syncthreads();
  }
  float r = red[0];
  __syncthreads();
  return r;
}

// ---------------- f32 VALU GEMM, 64x128 tile, 4x8 register tile: C = A * B ----------------
// Bit-identical accumulation order to the round-1 gemm_k (BK=16, kk ascending; per-output
// FMA order is independent of tile shape). vs round 4: smaller tile doubles the grid
// (occupancy was grid-limited at 30%), staggered Bs cols (4-way -> 2-way bank conflict),
// bijective XCD swizzle. Single-buffer two-barrier structure kept (round 5 showed
// dbuf+prefetch costs VGPR 64->132 and occupancy 30->10: net regression).
__global__ __launch_bounds__(256) void gemm_f32_k(const float* __restrict__ A, const float* __restrict__ Bw,
                                                  float* __restrict__ C, int N, int K)
{
  __shared__ float As[16][68];    // [k][m], m=64, pad 4
  __shared__ float Bs[16][140];   // [k][staggered n], n=128
  const int tid = threadIdx.x;
  const int gx = gridDim.x;
  const int nwg = gx * gridDim.y;          // both call sites: nwg % 8 == 0
  const int bid = blockIdx.y * gx + blockIdx.x;
  const int cpx = nwg >> 3;
  const int swz = (bid & 7) * cpx + (bid >> 3);
  const int m0 = (swz / gx) * 64, n0 = (swz % gx) * 128;

  const int tm = tid >> 4, tn = tid & 15;          // out: rows tm*4.., cols tn*8..
  const int am = tid >> 2, akq = (tid & 3) * 4;    // A staging: row am, k-quad akq
  const int bk = tid >> 4, bo = tid & 15;          // B staging: k-row bk, col-octet bo
  const int bg = bo * 8 + ((bo >> 2) << 2);        // staggered LDS col (write)
  const int tg = tn * 8 + ((tn >> 2) << 2);        // staggered LDS col (read)
  float acc[4][8] = {};

  for (int k0 = 0; k0 < K; k0 += 16){
    float4 av = ldA4(&A[(size_t)(m0 + am) * K + k0 + akq]);
    float4 b0 = ldA4(&Bw[(size_t)(k0 + bk) * N + n0 + bo*8]);
    float4 b1 = ldA4(&Bw[(size_t)(k0 + bk) * N + n0 + bo*8 + 4]);
    As[akq+0][am] = av.x; As[akq+1][am] = av.y; As[akq+2][am] = av.z; As[akq+3][am] = av.w;
    *reinterpret_cast<float4*>(&Bs[bk][bg])     = b0;
    *reinterpret_cast<float4*>(&Bs[bk][bg + 4]) = b1;
    __syncthreads();
    #pragma unroll
    for (int kk = 0; kk < 16; ++kk){
      float4 a4  = *reinterpret_cast<const float4*>(&As[kk][tm*4]);
      float4 bv0 = *reinterpret_cast<const float4*>(&Bs[kk][tg]);
      float4 bv1 = *reinterpret_cast<const float4*>(&Bs[kk][tg + 4]);
      float a[4] = {a4.x,a4.y,a4.z,a4.w};
      float b[8] = {bv0.x,bv0.y,bv0.z,bv0.w,bv1.x,bv1.y,bv1.z,bv1.w};
      #pragma unroll
      for (int i = 0; i < 4; ++i)
        #pragma unroll
        for (int j = 0; j < 8; ++j)
          acc[i][j] += a[i]*b[j];
    }
    __syncthreads();
  }
  #pragma unroll
  for (int i = 0; i < 4; ++i){
    int row = m0 + tm*4 + i;
    float* dst = &C[(size_t)row * N + n0 + tn*8];
    *reinterpret_cast<float4*>(dst)     = make_float4(acc[i][0], acc[i][1], acc[i][2], acc[i][3]);
    *reinterpret_cast<float4*>(dst + 4) = make_float4(acc[i][4], acc[i][5], acc[i][6], acc[i][7]);
  }
}

// ---------------- RoPE in-place on q,k inside qkv buffer ----------------
__global__ __launch_bounds__(256) void rope_k(float* __restrict__ qkv)
{
  int idx = blockIdx.x * 256 + threadIdx.x;
  int j  = idx & 31;
  int hh = (idx >> 5) % NH_;
  int t  = idx / (32 * NH_);
  int s  = t & (S_ - 1);
  double invf = pow(10000.0, -(double)j / 32.0);
  float ph = (float)((double)s * invf);
  float sn, cs;
  sincosf(ph, &sn, &cs);
  float* base = qkv + (size_t)t * 2304 + hh * 192;
  float q0 = base[j],    q1 = base[32+j];
  base[j]    = q0*cs - q1*sn;
  base[32+j] = q1*cs + q0*sn;
  float k0 = base[64+j], k1 = base[96+j];
  base[64+j] = k0*cs - k1*sn;
  base[96+j] = k1*cs + k0*sn;
}

// ---------------- MFMA flash attention (bf16 inputs, f32 accum) ----------------
// One block = (b, h, 64 q rows); 4 waves, each owns 16 q rows. KV tile = 64.
// LDS tiles are [row][72] shorts with col ^= ((row&12)<<1) XOR swizzle:
//   keeps every staged write and every b128 fragment read at <=2-way bank aliasing.
__global__ __launch_bounds__(256) void attn_mfma_k(const float* __restrict__ qkv,
                                                   const int* __restrict__ amask,
                                                   float* __restrict__ ctx)
{
  __shared__ __align__(16) short Kl[64*72];   // K tile bf16  [kv][d]
  __shared__ __align__(16) short Vt[64*72];   // V^T tile bf16 [d][kv]
  __shared__ __align__(16) short Pl[64*72];   // P tile bf16  [q][kv] (per-wave 16-row slices)
  const int tid = threadIdx.x;
  const int qt = blockIdx.x & 31;
  const int hh = (blockIdx.x >> 5) % NH_;
  const int b  = blockIdx.x / (32 * NH_);
  const size_t tb = (size_t)b * S_;
  const int q0 = qt * 64;
  const int lane = tid & 63, w = tid >> 6;
  const int quad = lane >> 4, l15 = lane & 15;
  const int swl = (l15 & 12) << 1;            // read-side swizzle key (row&12)<<1 with row=...+l15

  // Q fragments in registers: A-frag row = w*16 + l15, k = quad*8 + ks*32 + j. Pre-scaled by 1/8.
  bf16x8 qf[2];
  {
    const float* qrow = qkv + (tb + q0 + w*16 + l15) * 2304 + hh*192;
    #pragma unroll
    for (int ks = 0; ks < 2; ++ks){
      float4 f0 = ldA4(qrow + ks*32 + quad*8);
      float4 f1 = ldA4(qrow + ks*32 + quad*8 + 4);
      union { bf16x8 v; unsigned u[4]; } u;
      u.u[0] = f2bf(f0.x*0.125f) | (f2bf(f0.y*0.125f) << 16);
      u.u[1] = f2bf(f0.z*0.125f) | (f2bf(f0.w*0.125f) << 16);
      u.u[2] = f2bf(f1.x*0.125f) | (f2bf(f1.y*0.125f) << 16);
      u.u[3] = f2bf(f1.z*0.125f) | (f2bf(f1.w*0.125f) << 16);
      qf[ks] = u.v;
    }
  }

  f32x4 O[4];                                  // O[nd][r]: row = w*16+quad*4+r, d = nd*16+l15
  #pragma unroll
  for (int i = 0; i < 4; ++i) O[i] = (f32x4){0.f,0.f,0.f,0.f};
  float m_i[4] = {-3.0e38f,-3.0e38f,-3.0e38f,-3.0e38f};
  float l_i[4] = {0.f,0.f,0.f,0.f};

  for (int c = 0; c < 32; ++c){
    __syncthreads();   // all waves done reading Kl/Vt of previous tile
    // ---- stage K [kv][d] and V^T [d][kv] (f32 -> bf16), 512 slots of (2 kv-rows x 4 d) ----
    #pragma unroll
    for (int i = 0; i < 2; ++i){
      int idx = i*256 + tid;
      int rp = idx >> 4;                 // kv row-pair 0..31
      int c4 = (idx & 15) * 4;           // d group
      int r = rp * 2;
      const float* src = &qkv[(tb + c*64 + r) * 2304 + hh*192 + 64 + c4];
      float4 k0 = ldA4(src);
      float4 v0 = ldA4(src + 64);
      float4 k1 = ldA4(src + 2304);
      float4 v1 = ldA4(src + 2304 + 64);
      uint2 kw0, kw1;
      kw0.x = f2bf(k0.x) | (f2bf(k0.y) << 16); kw0.y = f2bf(k0.z) | (f2bf(k0.w) << 16);
      kw1.x = f2bf(k1.x) | (f2bf(k1.y) << 16); kw1.y = f2bf(k1.z) | (f2bf(k1.w) << 16);
      *reinterpret_cast<uint2*>(&Kl[ r   *72 + (c4 ^ (( r    & 12) << 1))]) = kw0;
      *reinterpret_cast<uint2*>(&Kl[(r+1)*72 + (c4 ^ (((r+1) & 12) << 1))]) = kw1;
      float vv0[4] = {v0.x,v0.y,v0.z,v0.w};
      float vv1[4] = {v1.x,v1.y,v1.z,v1.w};
      #pragma unroll
      for (int dd = 0; dd < 4; ++dd){
        int d = c4 + dd;
        unsigned pw = f2bf(vv0[dd]) | (f2bf(vv1[dd]) << 16);   // pack kv pair (r, r+1)
        *reinterpret_cast<unsigned*>(&Vt[d*72 + (r ^ ((d & 12) << 1))]) = pw;
      }
    }
    __syncthreads();

    // ---- S = Q K^T (per wave: 16 q rows x 64 kv cols) ----
    f32x4 sacc[4];
    #pragma unroll
    for (int ni = 0; ni < 4; ++ni) sacc[ni] = (f32x4){0.f,0.f,0.f,0.f};
    #pragma unroll
    for (int ks = 0; ks < 2; ++ks){
      #pragma unroll
      for (int ni = 0; ni < 4; ++ni){
        bf16x8 kf = *reinterpret_cast<const bf16x8*>(
            &Kl[(ni*16 + l15)*72 + ((quad*8 + ks*32) ^ swl)]);
        sacc[ni] = __builtin_amdgcn_mfma_f32_16x16x32_bf16(qf[ks], kf, sacc[ni], 0, 0, 0);
      }
    }

    // ---- mask + online softmax (rows = quad*4+r, cols = ni*16+l15) ----
    #pragma unroll
    for (int ni = 0; ni < 4; ++ni){
      int mv = amask[b*S_ + c*64 + ni*16 + l15];
      if (mv == 0){
        sacc[ni][0] = -3.0e38f; sacc[ni][1] = -3.0e38f;
        sacc[ni][2] = -3.0e38f; sacc[ni][3] = -3.0e38f;
      }
    }
    float p[4][4];
    #pragma unroll
    for (int r = 0; r < 4; ++r){
      float v = fmaxf(fmaxf(sacc[0][r], sacc[1][r]), fmaxf(sacc[2][r], sacc[3][r]));
      #pragma unroll
      for (int o = 8; o > 0; o >>= 1) v = fmaxf(v, __shfl_xor(v, o, 64));
      float mn = fmaxf(m_i[r], v);
      float al = __expf(m_i[r] - mn);
      m_i[r] = mn;
      float ts = 0.f;
      #pragma unroll
      for (int ni = 0; ni < 4; ++ni){
        float e = __expf(sacc[ni][r] - mn);
        p[ni][r] = e; ts += e;
      }
      #pragma unroll
      for (int o = 8; o > 0; o >>= 1) ts += __shfl_xor(ts, o, 64);
      l_i[r] = l_i[r]*al + ts;
      #pragma unroll
      for (int nd = 0; nd < 4; ++nd) O[nd][r] *= al;
    }

    // ---- P C-layout -> LDS (bf16) -> A-layout fragments (per-wave rows, no barrier) ----
    #pragma unroll
    for (int ni = 0; ni < 4; ++ni){
      int colp = (ni*16 + l15) ^ (quad << 3);   // ((q&12)<<1) == quad<<3 for rows quad*4+r
      #pragma unroll
      for (int r = 0; r < 4; ++r)
        Pl[(w*16 + quad*4 + r)*72 + colp] = (short)f2bf(p[ni][r]);
    }
    bf16x8 pa[2];
    #pragma unroll
    for (int ks = 0; ks < 2; ++ks)
      pa[ks] = *reinterpret_cast<const bf16x8*>(
          &Pl[(w*16 + l15)*72 + ((quad*8 + ks*32) ^ swl)]);

    // ---- O += P V ----
    #pragma unroll
    for (int ks = 0; ks < 2; ++ks){
      #pragma unroll
      for (int nd = 0; nd < 4; ++nd){
        bf16x8 vf = *reinterpret_cast<const bf16x8*>(
            &Vt[(nd*16 + l15)*72 + ((quad*8 + ks*32) ^ swl)]);
        O[nd] = __builtin_amdgcn_mfma_f32_16x16x32_bf16(pa[ks], vf, O[nd], 0, 0, 0);
      }
    }
  }

  // ---- epilogue: O / l ----
  #pragma unroll
  for (int r = 0; r < 4; ++r){
    float inv = 1.f / l_i[r];
    int row = q0 + w*16 + quad*4 + r;
    float* dst = &ctx[(tb + row)*H_ + hh*HD_ + l15];
    #pragma unroll
    for (int nd = 0; nd < 4; ++nd)
      dst[nd*16] = O[nd][r] * inv;
  }
}

// ---------------- norm1: x1 = rmsnorm(x + attn_out) * w ----------------
__global__ __launch_bounds__(256) void norm1_k(const float* __restrict__ x, const float* __restrict__ ao,
                                               const float* __restrict__ w, float* __restrict__ x1)
{
  __shared__ float red[256];
  const int t = blockIdx.x, tid = threadIdx.x;
  float y[3]; float ss = 0.f;
  #pragma unroll
  for (int k = 0; k < 3; ++k){
    int i = tid + k*256;
    y[k] = x[(size_t)t*H_ + i] + ao[(size_t)t*H_ + i];
    ss += y[k]*y[k];
  }
  float tot = block_sum256(ss, red);
  float r = rsqrtf(tot / 768.f + 1.1920928955078125e-07f);
  #pragma unroll
  for (int k = 0; k < 3; ++k){
    int i = tid + k*256;
    x1[(size_t)t*H_ + i] = y[k] * r * w[i];
  }
}

// ---------------- router: logits, softmax, top-2, stats ----------------
__global__ __launch_bounds__(256) void router_k(const float* __restrict__ x1, const float* __restrict__ gw,
                                                float* __restrict__ rw, int* __restrict__ sel,
                                                float* __restrict__ Psum, int* __restrict__ cnt)
{
  __shared__ float lg[8];
  __shared__ float pr[8];
  const int t = blockIdx.x, tid = threadIdx.x;
  const int e = tid >> 5, l = tid & 31;
  const float* xr = x1 + (size_t)t * H_;
  float p = 0.f;
  for (int k = l; k < H_; k += 32) p += xr[k] * gw[k*E_ + e];
  #pragma unroll
  for (int o = 16; o > 0; o >>= 1) p += __shfl_xor(p, o, 32);
  if (l == 0) lg[e] = p;
  __syncthreads();
  if (tid == 0){
    float m = lg[0];
    #pragma unroll
    for (int i = 1; i < 8; ++i) m = fmaxf(m, lg[i]);
    float pv[8]; float s = 0.f;
    #pragma unroll
    for (int i = 0; i < 8; ++i){ pv[i] = expf(lg[i] - m); s += pv[i]; }
    float invs = 1.f / s;
    #pragma unroll
    for (int i = 0; i < 8; ++i){ pv[i] *= invs; pr[i] = pv[i]; }
    int i0 = 0;
    for (int i = 1; i < 8; ++i) if (pv[i] > pv[i0]) i0 = i;
    int i1 = -1;
    for (int i = 0; i < 8; ++i){ if (i == i0) continue; if (i1 < 0 || pv[i] > pv[i1]) i1 = i; }
    float w0 = pv[i0], w1 = pv[i1], si = 1.f / (w0 + w1);
    rw[2*t] = w0*si; rw[2*t+1] = w1*si;
    sel[2*t] = i0;   sel[2*t+1] = i1;
    atomicAdd(&cnt[i0], 1); atomicAdd(&cnt[i1], 1);
  }
  __syncthreads();
  if (tid < 8) atomicAdd(&Psum[tid], pr[tid]);
}

// ---------------- offsets + aux loss ----------------
__global__ void offs_aux_k(const float* __restrict__ Psum, const int* __restrict__ cnt,
                           int* __restrict__ offs, float* __restrict__ aux_out)
{
  __shared__ float red[8];
  const int tid = threadIdx.x;
  if (tid == 0){
    int o = 0;
    for (int e = 0; e < 8; ++e){ offs[e] = o; o += cnt[e]; }
  }
  if (tid < 8) red[tid] = ((float)cnt[tid] / 8192.f) * (Psum[tid] / 8192.f);
  __syncthreads();
  if (tid == 0){
    float s = 0.f;
    for (int e = 0; e < 8; ++e) s += red[e];
    *aux_out = 8.f * s;
  }
}

// ---------------- scatter tokens into per-expert segments (+ per-assignment weight) ----------------
__global__ __launch_bounds__(256) void scatter_k(const int* __restrict__ sel, const int* __restrict__ offs,
                                                 const float* __restrict__ rw,
                                                 int* __restrict__ cur, int* __restrict__ toka,
                                                 float* __restrict__ wgt)
{
  int t = blockIdx.x*256 + threadIdx.x;
  if (t >= T_) return;
  #pragma unroll
  for (int j = 0; j < 2; ++j){
    int e = sel[2*t + j];
    int pos = atomicAdd(&cur[e], 1);
    int a = offs[e] + pos;
    toka[a] = t;
    wgt[a] = rw[2*t + j];
  }
}

// ---------------- tiled transpose + f32->bf16 convert: dst[C][R] = src[R][C] ----------------
__global__ __launch_bounds__(256) void transpose_conv_k(const float* __restrict__ src,
                                                        unsigned short* __restrict__ dst,
                                                        int R, int C)
{
  __shared__ float T[32][33];
  const float* s = src + (size_t)blockIdx.z * R * C;
  unsigned short* d = dst + (size_t)blockIdx.z * R * C;
  int r0 = blockIdx.y*32, c0 = blockIdx.x*32;
  int t = threadIdx.x;
  int r = t >> 3, c4 = (t & 7) * 4;
  float4 v = ldA4(&s[(size_t)(r0+r)*C + c0 + c4]);
  T[r][c4+0]=v.x; T[r][c4+1]=v.y; T[r][c4+2]=v.z; T[r][c4+3]=v.w;
  __syncthreads();
  int c = t >> 3, r4 = (t & 7) * 4;
  ushort4 o;
  o.x = (unsigned short)f2bf(T[r4+0][c]);
  o.y = (unsigned short)f2bf(T[r4+1][c]);
  o.z = (unsigned short)f2bf(T[r4+2][c]);
  o.w = (unsigned short)f2bf(T[r4+3][c]);
  *reinterpret_cast<ushort4*>(&d[(size_t)(c0+c)*R + r0 + r4]) = o;
}

// ---------------- MoE GEMM1 (MFMA bf16): hmid = gelu(x1[toka] @ w1T^T) ----------------
// 128x128 tile, BK=64, 4 waves; A staged f32->bf16 on the fly; B pre-transposed [F][H] bf16.
__global__ __launch_bounds__(256) void moe1_mfma_k(const float* __restrict__ X,
                                                   const unsigned short* __restrict__ Bt,
                                                   const int* __restrict__ offs,
                                                   const int* __restrict__ cnts,
                                                   const int* __restrict__ toka,
                                                   unsigned short* __restrict__ hmid)
{
  const int e = blockIdx.z;
  const int n_e = cnts[e];
  const int mt = blockIdx.y * 128;
  if (mt >= n_e) return;
  const int base = offs[e];
  const unsigned short* Bw = Bt + (size_t)e * (H_*F_);
  __shared__ __align__(16) short Al[8*129*8];
  __shared__ __align__(16) short Bl[8*129*8];
  const int tid = threadIdx.x;
  const int n0 = blockIdx.x * 128;
  int tokm[4];
  #pragma unroll
  for (int i = 0; i < 4; ++i){
    int m = (tid + i*256) >> 3;
    tokm[i] = toka[base + min(mt + m, n_e - 1)];
  }
  const int lane = tid & 63, w = tid >> 6;
  const int wr = w >> 1, wc = w & 1;
  const int quad = lane >> 4, l15 = lane & 15;
  f32x4 acc[4][4];
  #pragma unroll
  for (int a = 0; a < 4; ++a)
    #pragma unroll
    for (int b = 0; b < 4; ++b) acc[a][b] = (f32x4){0.f,0.f,0.f,0.f};

  for (int k0 = 0; k0 < H_; k0 += 64){
    __syncthreads();
    #pragma unroll
    for (int i = 0; i < 4; ++i){
      int c = tid + i*256;
      int m = c >> 3, kc = c & 7;
      const float* src = X + (size_t)tokm[i]*H_ + k0 + kc*8;
      float4 f0 = ldA4(src);
      float4 f1 = ldA4(src + 4);
      int4 pk;
      pk.x = (int)(f2bf(f0.x) | (f2bf(f0.y) << 16));
      pk.y = (int)(f2bf(f0.z) | (f2bf(f0.w) << 16));
      pk.z = (int)(f2bf(f1.x) | (f2bf(f1.y) << 16));
      pk.w = (int)(f2bf(f1.z) | (f2bf(f1.w) << 16));
      *reinterpret_cast<int4*>(&Al[(kc*129 + m)*8]) = pk;
      *reinterpret_cast<int4*>(&Bl[(kc*129 + m)*8]) =
        *reinterpret_cast<const int4*>(&Bw[(size_t)(n0 + m)*H_ + k0 + kc*8]);
    }
    __syncthreads();
    #pragma unroll
    for (int ks = 0; ks < 2; ++ks){
      bf16x8 af[4], bfr[4];
      #pragma unroll
      for (int mi = 0; mi < 4; ++mi)
        af[mi] = *reinterpret_cast<const bf16x8*>(&Al[((ks*4+quad)*129 + wr*64 + mi*16 + l15)*8]);
      #pragma unroll
      for (int ni = 0; ni < 4; ++ni)
        bfr[ni] = *reinterpret_cast<const bf16x8*>(&Bl[((ks*4+quad)*129 + wc*64 + ni*16 + l15)*8]);
      #pragma unroll
      for (int mi = 0; mi < 4; ++mi)
        #pragma unroll
        for (int ni = 0; ni < 4; ++ni)
          acc[mi][ni] = __builtin_amdgcn_mfma_f32_16x16x32_bf16(af[mi], bfr[ni], acc[mi][ni], 0, 0, 0);
    }
  }
  #pragma unroll
  for (int mi = 0; mi < 4; ++mi)
    #pragma unroll
    for (int r = 0; r < 4; ++r){
      int row = mt + wr*64 + mi*16 + quad*4 + r;
      if (row < n_e){
        unsigned short* dst = hmid + (size_t)(base + row)*F_ + n0 + wc*64 + l15;
        #pragma unroll
        for (int ni = 0; ni < 4; ++ni){
          float h = acc[mi][ni][r];
          float g = 0.5f * h * (1.f + erff(h * 0.70710678118654752f));
          dst[ni*16] = (unsigned short)f2bf(g);
        }
      }
    }
}

// ---------------- MoE GEMM2 (MFMA bf16): x1 += wgt * (hmid @ w2T^T) ----------------
__global__ __launch_bounds__(256) void moe2_mfma_k(const unsigned short* __restrict__ Hm,
                                                   const unsigned short* __restrict__ Bt,
                                                   const int* __restrict__ offs,
                                                   const int* __restrict__ cnts,
                                                   const int* __restrict__ toka,
                                                   const float* __restrict__ wgt,
                                                   float* __restrict__ x1acc)
{
  const int e = blockIdx.z;
  const int n_e = cnts[e];
  const int mt = blockIdx.y * 128;
  if (mt >= n_e) return;
  const int base = offs[e];
  const unsigned short* Bw = Bt + (size_t)e * (H_*F_);
  __shared__ __align__(16) short Al[8*129*8];
  __shared__ __align__(16) short Bl[8*129*8];
  const int tid = threadIdx.x;
  const int n0 = blockIdx.x * 128;
  const int lane = tid & 63, w = tid >> 6;
  const int wr = w >> 1, wc = w & 1;
  const int quad = lane >> 4, l15 = lane & 15;
  f32x4 acc[4][4];
  #pragma unroll
  for (int a = 0; a < 4; ++a)
    #pragma unroll
    for (int b = 0; b < 4; ++b) acc[a][b] = (f32x4){0.f,0.f,0.f,0.f};

  for (int k0 = 0; k0 < F_; k0 += 64){
    __syncthreads();
    #pragma unroll
    for (int i = 0; i < 4; ++i){
      int c = tid + i*256;
      int m = c >> 3, kc = c & 7;
      int hrow = base + min(mt + m, n_e - 1);
      *reinterpret_cast<int4*>(&Al[(kc*129 + m)*8]) =
        *reinterpret_cast<const int4*>(&Hm[(size_t)hrow*F_ + k0 + kc*8]);
      *reinterpret_cast<int4*>(&Bl[(kc*129 + m)*8]) =
        *reinterpret_cast<const int4*>(&Bw[(size_t)(n0 + m)*F_ + k0 + kc*8]);
    }
    __syncthreads();
    #pragma unroll
    for (int ks = 0; ks < 2; ++ks){
      bf16x8 af[4], bfr[4];
      #pragma unroll
      for (int mi = 0; mi < 4; ++mi)
        af[mi] = *reinterpret_cast<const bf16x8*>(&Al[((ks*4+quad)*129 + wr*64 + mi*16 + l15)*8]);
      #pragma unroll
      for (int ni = 0; ni < 4; ++ni)
        bfr[ni] = *reinterpret_cast<const bf16x8*>(&Bl[((ks*4+quad)*129 + wc*64 + ni*16 + l15)*8]);
      #pragma unroll
      for (int mi = 0; mi < 4; ++mi)
        #pragma unroll
        for (int ni = 0; ni < 4; ++ni)
          acc[mi][ni] = __builtin_amdgcn_mfma_f32_16x16x32_bf16(af[mi], bfr[ni], acc[mi][ni], 0, 0, 0);
    }
  }
  #pragma unroll
  for (int mi = 0; mi < 4; ++mi)
    #pragma unroll
    for (int r = 0; r < 4; ++r){
      int row = mt + wr*64 + mi*16 + quad*4 + r;
      if (row < n_e){
        int tok = toka[base + row];
        float wg = wgt[base + row];
        float* dst = x1acc + (size_t)tok*H_ + n0 + wc*64 + l15;
        #pragma unroll
        for (int ni = 0; ni < 4; ++ni)
          atomicAdd(&dst[ni*16], acc[mi][ni][r] * wg);
      }
    }
}

// ---------------- norm2: out = rmsnorm(x1_accumulated) * w ----------------
__global__ __launch_bounds__(256) void norm2_k(const float* __restrict__ x1acc,
                                               const float* __restrict__ w, float* __restrict__ out)
{
  __shared__ float red[256];
  const int t = blockIdx.x, tid = threadIdx.x;
  const float* xr = x1acc + (size_t)t * H_;
  float y[3]; float ss = 0.f;
  #pragma unroll
  for (int k = 0; k < 3; ++k){
    int i = tid + k*256;
    y[k] = xr[i];
    ss += y[k]*y[k];
  }
  float tot = block_sum256(ss, red);
  float r = rsqrtf(tot / 768.f + 1.1920928955078125e-07f);
  #pragma unroll
  for (int k = 0; k < 3; ++k){
    int i = tid + k*256;
    out[(size_t)t*H_ + i] = y[k] * r * w[i];
  }
}

extern "C" void kernel_launch(void* const* d_in, const int* in_sizes, int n_in,
                              void* d_out, int out_size, void* d_ws, size_t ws_size,
                              hipStream_t stream)
{
  const float* x      = (const float*)d_in[0];
  const int*   amask  = (const int*)  d_in[1];
  const float* qkv_w  = (const float*)d_in[2];
  const float* out_w  = (const float*)d_in[3];
  const float* gate_w = (const float*)d_in[4];
  const float* w1     = (const float*)d_in[5];
  const float* w2     = (const float*)d_in[6];
  const float* n1w    = (const float*)d_in[7];
  const float* n2w    = (const float*)d_in[8];

  char* ws = (char*)d_ws;
  // workspace layout (bytes), liveness-overlapped; total ~163.8 MB:
  //   [0, 75497472)            qkv f32 (P1-P3) -> attn f32 [0,25165824) (P4-P5) -> hmid bf16 [0,100663296) (P7-P8)
  //   [75497472, 100663296)    ctx f32 (P3-P4) -> hmid tail
  //   [100663296, 125829120)   x1 f32 (norm1 -> router/moe1; moe2 atomically accumulates; norm2 reads)
  //   [125829120, 163577856)   w1T bf16 (conv -> moe1), then w2T bf16 (conv -> moe2)
  //   [163577856, ...)         rw / sel / toka / wgt / stats
  float* qkv  = (float*)(ws);
  float* ctx  = (float*)(ws + 75497472);
  float* attn = (float*)(ws);
  float* x1   = (float*)(ws + 100663296);
  unsigned short* hmid = (unsigned short*)(ws);
  unsigned short* w1T  = (unsigned short*)(ws + 125829120);
  unsigned short* w2T  = (unsigned short*)(ws + 125829120);
  float* rw   = (float*)(ws + 163577856);
  int*   sel  = (int*)  (ws + 163643392);
  int*   toka = (int*)  (ws + 163708928);
  float* wgt  = (float*)(ws + 163774464);
  float* Psum = (float*)(ws + 163840000);
  int*   cnt  = (int*)  (ws + 163840032);
  int*   cur  = (int*)  (ws + 163840064);
  int*   offs = (int*)  (ws + 163840096);

  float* out_x2  = (float*)d_out;
  float* out_aux = out_x2 + 6291456;

  hipMemsetAsync(ws + 163840000, 0, 128, stream);  // Psum, cnt, cur, offs

  gemm_f32_k<<<dim3(18, 128), 256, 0, stream>>>(x, qkv_w, qkv, 2304, H_);
  rope_k<<<12288, 256, 0, stream>>>(qkv);
  attn_mfma_k<<<1536, 256, 0, stream>>>(qkv, amask, ctx);
  gemm_f32_k<<<dim3(6, 128), 256, 0, stream>>>(ctx, out_w, attn, H_, H_);
  norm1_k<<<T_, 256, 0, stream>>>(x, attn, n1w, x1);
  router_k<<<T_, 256, 0, stream>>>(x1, gate_w, rw, sel, Psum, cnt);
  offs_aux_k<<<1, 64, 0, stream>>>(Psum, cnt, offs, out_aux);
  scatter_k<<<32, 256, 0, stream>>>(sel, offs, rw, cur, toka, wgt);
  transpose_conv_k<<<dim3(96, 24, 8), 256, 0, stream>>>(w1, w1T, H_, F_);   // w1T[e][F][H]
  moe1_mfma_k<<<dim3(24, 64, 8), 256, 0, stream>>>(x1, w1T, offs, cnt, toka, hmid);
  transpose_conv_k<<<dim3(24, 96, 8), 256, 0, stream>>>(w2, w2T, F_, H_);   // w2T[e][H][F]
  moe2_mfma_k<<<dim3(6, 64, 8), 256, 0, stream>>>(hmid, w2T, offs, cnt, toka, wgt, x1);
  norm2_k<<<T_, 256, 0, stream>>>(x1, n2w, out_x2);
}